// Round 2
// baseline (289.147 us; speedup 1.0000x reference)
//
#include <hip/hip_runtime.h>

// Problem constants (from reference)
#define B_    16
#define C_    64
#define HDIM  192
#define WDIM  192
#define HW    (HDIM * WDIM)   // 36864
#define P_    128
#define L_    512
#define STEPS (P_ * L_)       // 65536 steps per batch

// ---------------------------------------------------------------------------
// Kernel 1: mark visited pixels. Each thread consumes 4 int32 indices.
// Races (multiple threads storing 1 to the same byte) are benign.
// ---------------------------------------------------------------------------
__global__ __launch_bounds__(256) void touch_kernel(const int* __restrict__ idx,
                                                    unsigned char* __restrict__ mask) {
    int t = blockIdx.x * blockDim.x + threadIdx.x;   // int4 id
    const int4 v = ((const int4*)idx)[t];
    int b = (t * 4) >> 16;                           // 65536 steps per batch; 4 elems share b
    unsigned char* mb = mask + (size_t)b * HW;
    mb[v.x] = 1;
    mb[v.y] = 1;
    mb[v.z] = 1;
    mb[v.w] = 1;
}

// ---------------------------------------------------------------------------
// Kernel 2: out[b, j, p] = mask[b,p] ? (sum_c feat[b,c,p] * W[c,j] + bias[j]) : 0
// Block = 256 threads = 4 waves. Each block owns 64 consecutive pixels.
// Stage feat tile [64 ch][64 px] in LDS (16 KB). Wave w computes output
// channels [w*16, w*16+16); lane owns pixel (t & 63). W/bias read through
// wave-uniform addresses -> scalar cache.
// ---------------------------------------------------------------------------
__global__ __launch_bounds__(256) void mm_mask_kernel(const float* __restrict__ feat,
                                                      const float* __restrict__ Wm,
                                                      const float* __restrict__ bm,
                                                      const unsigned char* __restrict__ mask,
                                                      float* __restrict__ out) {
    __shared__ float ldsF[C_ * 64];   // [channel][pixel], 16 KB

    const int t     = threadIdx.x;
    const int blk   = blockIdx.x;
    const int b     = blk / (HW / 64);
    const int chunk = blk % (HW / 64);
    const int hw0   = chunk * 64;

    // ---- stage tile: 64 channels x 64 pixels, float4 coalesced ----
    const float* fbase = feat + (size_t)b * C_ * HW + hw0;
#pragma unroll
    for (int r = 0; r < 4; ++r) {
        int id = r * 256 + t;        // float4 id in [0,1024)
        int c  = id >> 4;            // 16 float4 per channel row
        int q  = id & 15;
        float4 v = *(const float4*)(fbase + (size_t)c * HW + q * 4);
        *(float4*)(&ldsF[c * 64 + q * 4]) = v;
    }
    __syncthreads();

    const int px = t & 63;
    const int c0 = __builtin_amdgcn_readfirstlane((t >> 6) * 16);  // wave-uniform

    float acc[16];
#pragma unroll
    for (int i = 0; i < 16; ++i) acc[i] = bm[c0 + i];

#pragma unroll
    for (int kb = 0; kb < C_; kb += 4) {
        float f[4];
#pragma unroll
        for (int j = 0; j < 4; ++j) f[j] = ldsF[(kb + j) * 64 + px];  // 2-way/bank: free
#pragma unroll
        for (int j = 0; j < 4; ++j) {
            const float* wrow = Wm + (kb + j) * C_ + c0;   // wave-uniform -> s_load
#pragma unroll
            for (int i = 0; i < 16; ++i) acc[i] += f[j] * wrow[i];
        }
    }

    const float msk = mask[(size_t)b * HW + hw0 + px] ? 1.0f : 0.0f;
    float* obase = out + (size_t)b * C_ * HW + hw0 + px;
#pragma unroll
    for (int i = 0; i < 16; ++i)
        obase[(size_t)(c0 + i) * HW] = acc[i] * msk;   // 256B coalesced per row
}

// ---------------------------------------------------------------------------
extern "C" void kernel_launch(void* const* d_in, const int* in_sizes, int n_in,
                              void* d_out, int out_size, void* d_ws, size_t ws_size,
                              hipStream_t stream) {
    const float*         feat = (const float*)d_in[0];
    const int*           idx  = (const int*)d_in[1];
    const float*         Wm   = (const float*)d_in[2];
    const float*         bm   = (const float*)d_in[3];
    float*               out  = (float*)d_out;
    unsigned char*       mask = (unsigned char*)d_ws;

    // zero the visited mask (B*HW bytes = 589,824)
    hipMemsetAsync(mask, 0, (size_t)B_ * HW, stream);

    // mark visited pixels: B*STEPS/4 int4-threads
    const int touch_threads = (B_ * STEPS) / 4;     // 262,144
    touch_kernel<<<touch_threads / 256, 256, 0, stream>>>(idx, mask);

    // masked per-pixel linear transform
    mm_mask_kernel<<<B_ * (HW / 64), 256, 0, stream>>>(feat, Wm, bm, mask, out);
}